// Round 5
// baseline (337.895 us; speedup 1.0000x reference)
//
#include <hip/hip_runtime.h>
#include <hip/hip_bf16.h>
#include <math.h>

using bf16 = __hip_bfloat16;
using bf162 = __hip_bfloat162;

typedef __bf16 bf16x8 __attribute__((ext_vector_type(8)));
typedef float floatx4 __attribute__((ext_vector_type(4)));

constexpr int NB = 4, HH = 96, WW = 96, CC = 128, GG = 8, PP = 9;
constexpr int HW = HH * WW;          // 9216
constexpr int NPIX = NB * HW;        // 36864

__device__ __forceinline__ float ld1(const float* p) { return *p; }
__device__ __forceinline__ float ld1(const bf16* p)  { return __bfloat162float(*p); }
__device__ __forceinline__ void st1(float* p, float v) { *p = v; }
__device__ __forceinline__ void st1(bf16* p, float v)  { *p = __float2bfloat16(v); }
__device__ __forceinline__ float b2f(bf16 v) { return __bfloat162float(v); }
__device__ __forceinline__ bf16 f2b(float v) { return __float2bfloat16(v); }
__device__ __forceinline__ float gelu_exact(float v) {
    return 0.5f * v * (1.0f + erff(v * 0.7071067811865475f));
}

// ---------------- one-time weight prep: f32 W[K][N] -> bf16 Wt[N][K] (+ bias concat)
struct PrepArgs {
    const float* src[6];
    bf16* dst[6];
    int K[6], N[6];
    int cum[7];
    const float* b_off; const float* b_msk; float* b_om;   // bias concat 216
};

__global__ __launch_bounds__(256) void prep_weights(PrepArgs pa, int total)
{
    int t = blockIdx.x * 256 + threadIdx.x;
    if (t >= total) return;
    if (t >= pa.cum[6]) {                 // bias concat tail
        int e = t - pa.cum[6];
        pa.b_om[e] = (e < 144) ? pa.b_off[e] : pa.b_msk[e - 144];
        return;
    }
    int i = 0;
    #pragma unroll
    for (int j = 0; j < 5; ++j) if (t >= pa.cum[j + 1]) i = j + 1;
    int e = t - pa.cum[i];
    int Ki = pa.K[i], Ni = pa.N[i];
    int n = e / Ki, k = e - n * Ki;
    pa.dst[i][e] = f2b(pa.src[i][(size_t)k * Ni + n]);
}

// ---------------- LayerNorm over C=128, one wave per pixel, 2 ch/lane
template<typename TI, typename TO>
__global__ __launch_bounds__(256) void ln_kernel(
    const TI* __restrict__ X, const float* __restrict__ g,
    const float* __restrict__ b, TO* __restrict__ out)
{
    int wave = (blockIdx.x * 256 + threadIdx.x) >> 6;
    int lane = threadIdx.x & 63;
    if (wave >= NPIX) return;
    const TI* xp = X + (size_t)wave * 128 + 2 * lane;
    float v0 = ld1(xp), v1 = ld1(xp + 1);
    float s = v0 + v1, q = v0 * v0 + v1 * v1;
    #pragma unroll
    for (int o = 32; o; o >>= 1) { s += __shfl_xor(s, o); q += __shfl_xor(q, o); }
    float mean = s * (1.0f / 128.0f);
    float rstd = rsqrtf(q * (1.0f / 128.0f) - mean * mean + 1e-5f);
    float g0 = g[2 * lane], g1 = g[2 * lane + 1];
    float b0 = b[2 * lane], b1 = b[2 * lane + 1];
    TO* op = out + (size_t)wave * 128 + 2 * lane;
    st1(op,     (v0 - mean) * rstd * g0 + b0);
    st1(op + 1, (v1 - mean) * rstd * g1 + b1);
}

// ---------------- depthwise 3x3 conv (SAME, zero pad) + LN + exact GELU. wave/pixel
__global__ __launch_bounds__(256) void dwconv_ln_gelu_kernel(
    const bf16* __restrict__ xln, const float* __restrict__ dwk,
    const float* __restrict__ dwb, const float* __restrict__ gam,
    const float* __restrict__ bet, bf16* __restrict__ out)
{
    int wave = (blockIdx.x * 256 + threadIdx.x) >> 6;
    int lane = threadIdx.x & 63;
    if (wave >= NPIX) return;
    int n = wave / HW; int rem = wave % HW;
    int y = rem / WW;  int x = rem % WW;
    const bf162* xp = (const bf162*)xln;
    float a0 = 0.f, a1 = 0.f;
    #pragma unroll
    for (int ky = 0; ky < 3; ++ky) {
        int yy = y + ky - 1;
        if (yy < 0 || yy >= HH) continue;
        #pragma unroll
        for (int kx = 0; kx < 3; ++kx) {
            int xx = x + kx - 1;
            if (xx < 0 || xx >= WW) continue;
            bf162 v = xp[((size_t)(n * HH + yy) * WW + xx) * 64 + lane];
            const float* w = dwk + (ky * 3 + kx) * CC + 2 * lane;
            a0 = fmaf(b2f(v.x), w[0], a0);
            a1 = fmaf(b2f(v.y), w[1], a1);
        }
    }
    a0 += dwb[2 * lane]; a1 += dwb[2 * lane + 1];
    float s = a0 + a1, q = a0 * a0 + a1 * a1;
    #pragma unroll
    for (int o = 32; o; o >>= 1) { s += __shfl_xor(s, o); q += __shfl_xor(q, o); }
    float mean = s * (1.0f / 128.0f);
    float rstd = rsqrtf(q * (1.0f / 128.0f) - mean * mean + 1e-5f);
    float h0 = gelu_exact((a0 - mean) * rstd * gam[2 * lane]     + bet[2 * lane]);
    float h1 = gelu_exact((a1 - mean) * rstd * gam[2 * lane + 1] + bet[2 * lane + 1]);
    bf162 o2; o2.x = f2b(h0); o2.y = f2b(h1);
    ((bf162*)out)[(size_t)wave * 64 + lane] = o2;
}

// ---------------- DCNv3 core: wave per pixel, fused mask-softmax + two-phase
// omr[pix][216]: cols 0..143 = offsets, 144..215 = raw mask logits.
__global__ __launch_bounds__(256) void dcn_core_kernel(
    const bf16* __restrict__ xproj, const bf16* __restrict__ omr,
    bf16* __restrict__ out)
{
    __shared__ int4   sOff[4][72];
    __shared__ float4 sW[4][72];
    __shared__ float  sRaw[4][72];
    int wv = threadIdx.x >> 6;
    int lane = threadIdx.x & 63;
    int pix = blockIdx.x * 4 + wv;
    int n = pix / HW; int rem = pix % HW;
    int iy = rem / WW; int ix = rem % WW;
    const bf16* om = omr + (size_t)pix * 216;

    // phase 0: raw mask logits -> LDS
    for (int e = lane; e < 72; e += 64)
        sRaw[wv][e] = b2f(om[144 + e]);
    __syncthreads();

    // phase 1: 72 (group,point) bilinear records, softmax inline
    for (int e = lane; e < 72; e += 64) {
        int g = e / 9, p = e - 9 * g;
        float mx = -1e30f;
        #pragma unroll
        for (int i = 0; i < 9; ++i) mx = fmaxf(mx, sRaw[wv][g * 9 + i]);
        float ssum = 0.f;
        #pragma unroll
        for (int i = 0; i < 9; ++i) ssum += __expf(sRaw[wv][g * 9 + i] - mx);
        float mw = __expf(sRaw[wv][e] - mx) / ssum;

        float ox = b2f(om[g * 18 + 2 * p]);
        float oy = b2f(om[g * 18 + 2 * p + 1]);
        int kx = p / 3 - 1, ky = p % 3 - 1;  // torch meshgrid 'ij': x slowest
        float px = (float)(ix + kx) + ox;
        float py = (float)(iy + ky) + oy;
        float fx0 = floorf(px), fy0 = floorf(py);
        int x0 = (int)fx0, y0 = (int)fy0;
        float fx = px - fx0, fy = py - fy0;
        bool vx0 = (x0 >= 0) & (x0 < WW), vx1 = (x0 + 1 >= 0) & (x0 + 1 < WW);
        bool vy0 = (y0 >= 0) & (y0 < HH), vy1 = (y0 + 1 >= 0) & (y0 + 1 < HH);
        float w00 = (1.f - fy) * (1.f - fx) * mw * (vy0 && vx0 ? 1.f : 0.f);
        float w01 = (1.f - fy) * fx         * mw * (vy0 && vx1 ? 1.f : 0.f);
        float w10 = fy * (1.f - fx)         * mw * (vy1 && vx0 ? 1.f : 0.f);
        float w11 = fy * fx                 * mw * (vy1 && vx1 ? 1.f : 0.f);
        int x0c = min(max(x0, 0), WW - 1), x1c = min(max(x0 + 1, 0), WW - 1);
        int y0c = min(max(y0, 0), HH - 1), y1c = min(max(y0 + 1, 0), HH - 1);
        sOff[wv][e] = make_int4((y0c * WW + x0c) * CC, (y0c * WW + x1c) * CC,
                                (y1c * WW + x0c) * CC, (y1c * WW + x1c) * CC);
        sW[wv][e] = make_float4(w00, w01, w10, w11);
    }
    __syncthreads();

    // phase 2: lane = channel pair
    const bf16* xb = xproj + (size_t)n * HW * CC + 2 * lane;
    int gbase = (lane >> 3) * 9;
    float a0 = 0.f, a1 = 0.f;
    #pragma unroll
    for (int p = 0; p < 9; ++p) {
        int4 o = sOff[wv][gbase + p];
        float4 w = sW[wv][gbase + p];
        bf162 v00 = *(const bf162*)(xb + o.x);
        bf162 v01 = *(const bf162*)(xb + o.y);
        bf162 v10 = *(const bf162*)(xb + o.z);
        bf162 v11 = *(const bf162*)(xb + o.w);
        a0 += w.x * b2f(v00.x) + w.y * b2f(v01.x) + w.z * b2f(v10.x) + w.w * b2f(v11.x);
        a1 += w.x * b2f(v00.y) + w.y * b2f(v01.y) + w.z * b2f(v10.y) + w.w * b2f(v11.y);
    }
    bf162 o2; o2.x = f2b(a0); o2.y = f2b(a1);
    ((bf162*)out)[(size_t)pix * 64 + lane] = o2;
}

// ---------------- LDS-free register-direct MFMA GEMM
// Out[M,N] = act(A[M,K] @ W[K,N] + bias) (+R). A bf16 [M,K]; Wt bf16 [N,K]; bias f32.
// Block = 4 waves stacked along M (BM=64); each wave computes 16 rows x 64 cols.
// A-frags and B-frags loaded straight from global (16 rows x 64B per instr = 16 full
// cache lines, zero overfetch; Wt is L2-hot). No LDS, no barriers, no vmcnt(0) drains.
template<typename TR, typename TO>
__global__ __launch_bounds__(256, 4) void gemm_reg_kernel(
    const bf16* __restrict__ A, const bf16* __restrict__ Wt,
    const float* __restrict__ bias, const TR* __restrict__ R,
    TO* __restrict__ Out, int M, int Nn, int K, int act)
{
    int tid = threadIdx.x;
    int wv = tid >> 6, lane = tid & 63;
    int mI = lane & 15, q = lane >> 4;
    int bmw = blockIdx.y * 64 + wv * 16;       // wave's first row
    int bn = blockIdx.x * 64;

    const bf16* ap = A + (size_t)(bmw + mI) * K + q * 8;
    const bf16* bp[4];
    #pragma unroll
    for (int j = 0; j < 4; ++j) {
        int ng = min(bn + j * 16 + mI, Nn - 1);
        bp[j] = Wt + (size_t)ng * K + q * 8;
    }

    floatx4 acc[4] = {};
    for (int kb = 0; kb < K; kb += 128) {
        #pragma unroll
        for (int kk = 0; kk < 4; ++kk) {
            int ko = kb + kk * 32;
            bf16x8 a = *reinterpret_cast<const bf16x8*>(ap + ko);
            bf16x8 b0 = *reinterpret_cast<const bf16x8*>(bp[0] + ko);
            bf16x8 b1 = *reinterpret_cast<const bf16x8*>(bp[1] + ko);
            bf16x8 b2 = *reinterpret_cast<const bf16x8*>(bp[2] + ko);
            bf16x8 b3 = *reinterpret_cast<const bf16x8*>(bp[3] + ko);
            acc[0] = __builtin_amdgcn_mfma_f32_16x16x32_bf16(a, b0, acc[0], 0, 0, 0);
            acc[1] = __builtin_amdgcn_mfma_f32_16x16x32_bf16(a, b1, acc[1], 0, 0, 0);
            acc[2] = __builtin_amdgcn_mfma_f32_16x16x32_bf16(a, b2, acc[2], 0, 0, 0);
            acc[3] = __builtin_amdgcn_mfma_f32_16x16x32_bf16(a, b3, acc[3], 0, 0, 0);
        }
    }
    // epilogue: C/D layout col = lane&15, row = q*4 + r
    int row0 = bmw + q * 4;
    #pragma unroll
    for (int j = 0; j < 4; ++j) {
        int col = bn + j * 16 + mI;
        if (col >= Nn) continue;
        float bs = bias[col];
        #pragma unroll
        for (int r = 0; r < 4; ++r) {
            int row = row0 + r;
            float v = acc[j][r] + bs;
            if (act == 1) v = gelu_exact(v);
            if (R) v += ld1(R + (size_t)row * Nn + col);
            st1(Out + (size_t)row * Nn + col, v);
        }
    }
}

extern "C" void kernel_launch(void* const* d_in, const int* in_sizes, int n_in,
                              void* d_out, int out_size, void* d_ws, size_t ws_size,
                              hipStream_t stream)
{
    const float* x     = (const float*)d_in[0];
    const float* ln1g  = (const float*)d_in[1];
    const float* ln1b  = (const float*)d_in[2];
    const float* w_in  = (const float*)d_in[3];
    const float* b_in  = (const float*)d_in[4];
    const float* dw_k  = (const float*)d_in[5];
    const float* dw_b  = (const float*)d_in[6];
    const float* dwg   = (const float*)d_in[7];
    const float* dwb   = (const float*)d_in[8];
    const float* w_off = (const float*)d_in[9];
    const float* b_off = (const float*)d_in[10];
    const float* w_msk = (const float*)d_in[11];
    const float* b_msk = (const float*)d_in[12];
    const float* w_out = (const float*)d_in[13];
    const float* b_out = (const float*)d_in[14];
    const float* ln2g  = (const float*)d_in[15];
    const float* ln2b  = (const float*)d_in[16];
    const float* w1    = (const float*)d_in[17];
    const float* b1    = (const float*)d_in[18];
    const float* w2    = (const float*)d_in[19];
    const float* b2    = (const float*)d_in[20];
    float* out = (float*)d_out;

    // activations (bf16): xln(128)->ycore | xproj(128)->h2 | x1(128)->xres | reg4: omr(216)->h1(512)
    bf16* ws = (bf16*)d_ws;
    bf16* xln   = ws;
    bf16* xproj = xln   + (size_t)NPIX * 128;
    bf16* x1    = xproj + (size_t)NPIX * 128;
    bf16* reg4  = x1    + (size_t)NPIX * 128;
    bf16* omr   = reg4;                 // 216/pix, dead after dcn
    bf16* h1    = reg4;                 // 512/pix, born after dcn
    bf16* ycore = xln;
    bf16* xres  = x1;
    bf16* h2    = xproj;
    // bf16 transposed weights after activations (896/pix)
    bf16* wT    = ws + (size_t)NPIX * 896;
    bf16* w_inT  = wT;                  // 128x128
    bf16* w_omT  = w_inT  + 16384;      // 216x128 (off 144 + msk 72)
    bf16* w_outT = w_omT  + 27648;      // 128x128
    bf16* w1T    = w_outT + 16384;      // 512x128
    bf16* w2T    = w1T    + 65536;      // 128x512
    float* b_om  = (float*)(w2T + 65536);  // 216 f32
    const int WTOT = 191488 + 216;

    PrepArgs pa;
    pa.src[0] = w_in;  pa.dst[0] = w_inT;            pa.K[0] = 128; pa.N[0] = 128;
    pa.src[1] = w_off; pa.dst[1] = w_omT;            pa.K[1] = 128; pa.N[1] = 144;
    pa.src[2] = w_msk; pa.dst[2] = w_omT + 144*128;  pa.K[2] = 128; pa.N[2] = 72;
    pa.src[3] = w_out; pa.dst[3] = w_outT;           pa.K[3] = 128; pa.N[3] = 128;
    pa.src[4] = w1;    pa.dst[4] = w1T;              pa.K[4] = 128; pa.N[4] = 512;
    pa.src[5] = w2;    pa.dst[5] = w2T;              pa.K[5] = 512; pa.N[5] = 128;
    pa.cum[0] = 0;     pa.cum[1] = 16384;  pa.cum[2] = 34816; pa.cum[3] = 44032;
    pa.cum[4] = 60416; pa.cum[5] = 125952; pa.cum[6] = 191488;
    pa.b_off = b_off;  pa.b_msk = b_msk;   pa.b_om = b_om;

    const int M = NPIX;          // 36864, M/64 = 576
    dim3 blk(256);

    // 0. weight prep (+ bias concat)
    prep_weights<<<(WTOT + 255) / 256, blk, 0, stream>>>(pa, WTOT);
    // 1. xln = LN1(x)
    ln_kernel<float, bf16><<<NPIX / 4, blk, 0, stream>>>(x, ln1g, ln1b, xln);
    // 2. xproj = xln @ w_in + b_in
    gemm_reg_kernel<float, bf16><<<dim3(2, M / 64), blk, 0, stream>>>(
        xln, w_inT, b_in, (const float*)nullptr, xproj, M, 128, 128, 0);
    // 3. x1 = gelu(LN(dwconv(xln) + dw_b))
    dwconv_ln_gelu_kernel<<<NPIX / 4, blk, 0, stream>>>(xln, dw_k, dw_b, dwg, dwb, x1);
    // 4. omr = x1 @ [w_off | w_msk] + [b_off | b_msk]   (N=216 fused)
    gemm_reg_kernel<float, bf16><<<dim3(4, M / 64), blk, 0, stream>>>(
        x1, w_omT, b_om, (const float*)nullptr, omr, M, 216, 128, 0);
    // 5. ycore = dcnv3(xproj, omr)  [softmax fused in]
    dcn_core_kernel<<<NPIX / 4, blk, 0, stream>>>(xproj, omr, ycore);
    // 6. xres = x + ycore @ w_out + b_out
    gemm_reg_kernel<float, bf16><<<dim3(2, M / 64), blk, 0, stream>>>(
        ycore, w_outT, b_out, x, xres, M, 128, 128, 0);
    // 7. h2 = LN2(xres)
    ln_kernel<bf16, bf16><<<NPIX / 4, blk, 0, stream>>>(xres, ln2g, ln2b, h2);
    // 8. h1 = gelu(h2 @ w1 + b1)
    gemm_reg_kernel<float, bf16><<<dim3(8, M / 64), blk, 0, stream>>>(
        h2, w1T, b1, (const float*)nullptr, h1, M, 512, 128, 1);
    // 9. out = xres + h1 @ w2 + b2
    gemm_reg_kernel<bf16, float><<<dim3(2, M / 64), blk, 0, stream>>>(
        h1, w2T, b2, xres, out, M, 128, 512, 0);
}

// Round 7
// 245.217 us; speedup vs baseline: 1.3779x; 1.3779x over previous
//
#include <hip/hip_runtime.h>
#include <hip/hip_bf16.h>
#include <math.h>

using bf16 = __hip_bfloat16;
using bf162 = __hip_bfloat162;

typedef __bf16 bf16x8 __attribute__((ext_vector_type(8)));
typedef float floatx4 __attribute__((ext_vector_type(4)));

constexpr int NB = 4, HH = 96, WW = 96, CC = 128, GG = 8, PP = 9;
constexpr int HW = HH * WW;          // 9216
constexpr int NPIX = NB * HW;        // 36864

__device__ __forceinline__ float ld1(const float* p) { return *p; }
__device__ __forceinline__ float ld1(const bf16* p)  { return __bfloat162float(*p); }
__device__ __forceinline__ void st1(float* p, float v) { *p = v; }
__device__ __forceinline__ void st1(bf16* p, float v)  { *p = __float2bfloat16(v); }
__device__ __forceinline__ float b2f(bf16 v) { return __bfloat162float(v); }
__device__ __forceinline__ bf16 f2b(float v) { return __float2bfloat16(v); }
__device__ __forceinline__ float gelu_exact(float v) {
    return 0.5f * v * (1.0f + erff(v * 0.7071067811865475f));
}
__device__ __forceinline__ floatx4 MFMA(bf16x8 a, bf16x8 b, floatx4 c) {
    return __builtin_amdgcn_mfma_f32_16x16x32_bf16(a, b, c, 0, 0, 0);
}

// ---------------- one-time weight prep: f32 W[K][N] -> bf16 Wt[N][K] (+ bias concat)
struct PrepArgs {
    const float* src[6];
    bf16* dst[6];
    int K[6], N[6];
    int cum[7];
    const float* b_off; const float* b_msk; float* b_om;   // bias concat 216
};

__global__ __launch_bounds__(256) void prep_weights(PrepArgs pa, int total)
{
    int t = blockIdx.x * 256 + threadIdx.x;
    if (t >= total) return;
    if (t >= pa.cum[6]) {                 // bias concat tail
        int e = t - pa.cum[6];
        pa.b_om[e] = (e < 144) ? pa.b_off[e] : pa.b_msk[e - 144];
        return;
    }
    int i = 0;
    #pragma unroll
    for (int j = 0; j < 5; ++j) if (t >= pa.cum[j + 1]) i = j + 1;
    int e = t - pa.cum[i];
    int Ki = pa.K[i], Ni = pa.N[i];
    int n = e / Ki, k = e - n * Ki;
    pa.dst[i][e] = f2b(pa.src[i][(size_t)k * Ni + n]);
}

// ---------------- LayerNorm over C=128, one wave per pixel, 2 ch/lane
template<typename TI, typename TO>
__global__ __launch_bounds__(256) void ln_kernel(
    const TI* __restrict__ X, const float* __restrict__ g,
    const float* __restrict__ b, TO* __restrict__ out)
{
    int wave = (blockIdx.x * 256 + threadIdx.x) >> 6;
    int lane = threadIdx.x & 63;
    if (wave >= NPIX) return;
    const TI* xp = X + (size_t)wave * 128 + 2 * lane;
    float v0 = ld1(xp), v1 = ld1(xp + 1);
    float s = v0 + v1, q = v0 * v0 + v1 * v1;
    #pragma unroll
    for (int o = 32; o; o >>= 1) { s += __shfl_xor(s, o); q += __shfl_xor(q, o); }
    float mean = s * (1.0f / 128.0f);
    float rstd = rsqrtf(q * (1.0f / 128.0f) - mean * mean + 1e-5f);
    float g0 = g[2 * lane], g1 = g[2 * lane + 1];
    float b0 = b[2 * lane], b1 = b[2 * lane + 1];
    TO* op = out + (size_t)wave * 128 + 2 * lane;
    st1(op,     (v0 - mean) * rstd * g0 + b0);
    st1(op + 1, (v1 - mean) * rstd * g1 + b1);
}

// ---------------- depthwise 3x3 conv (SAME, zero pad) + LN + exact GELU. wave/pixel
__global__ __launch_bounds__(256) void dwconv_ln_gelu_kernel(
    const bf16* __restrict__ xln, const float* __restrict__ dwk,
    const float* __restrict__ dwb, const float* __restrict__ gam,
    const float* __restrict__ bet, bf16* __restrict__ out)
{
    int wave = (blockIdx.x * 256 + threadIdx.x) >> 6;
    int lane = threadIdx.x & 63;
    if (wave >= NPIX) return;
    int n = wave / HW; int rem = wave % HW;
    int y = rem / WW;  int x = rem % WW;
    const bf162* xp = (const bf162*)xln;
    float a0 = 0.f, a1 = 0.f;
    #pragma unroll
    for (int ky = 0; ky < 3; ++ky) {
        int yy = y + ky - 1;
        if (yy < 0 || yy >= HH) continue;
        #pragma unroll
        for (int kx = 0; kx < 3; ++kx) {
            int xx = x + kx - 1;
            if (xx < 0 || xx >= WW) continue;
            bf162 v = xp[((size_t)(n * HH + yy) * WW + xx) * 64 + lane];
            const float* w = dwk + (ky * 3 + kx) * CC + 2 * lane;
            a0 = fmaf(b2f(v.x), w[0], a0);
            a1 = fmaf(b2f(v.y), w[1], a1);
        }
    }
    a0 += dwb[2 * lane]; a1 += dwb[2 * lane + 1];
    float s = a0 + a1, q = a0 * a0 + a1 * a1;
    #pragma unroll
    for (int o = 32; o; o >>= 1) { s += __shfl_xor(s, o); q += __shfl_xor(q, o); }
    float mean = s * (1.0f / 128.0f);
    float rstd = rsqrtf(q * (1.0f / 128.0f) - mean * mean + 1e-5f);
    float h0 = gelu_exact((a0 - mean) * rstd * gam[2 * lane]     + bet[2 * lane]);
    float h1 = gelu_exact((a1 - mean) * rstd * gam[2 * lane + 1] + bet[2 * lane + 1]);
    bf162 o2; o2.x = f2b(h0); o2.y = f2b(h1);
    ((bf162*)out)[(size_t)wave * 64 + lane] = o2;
}

// ---------------- DCNv3 core: wave per pixel, fused mask-softmax + two-phase
__global__ __launch_bounds__(256) void dcn_core_kernel(
    const bf16* __restrict__ xproj, const bf16* __restrict__ omr,
    bf16* __restrict__ out)
{
    __shared__ int4   sOff[4][72];
    __shared__ float4 sW[4][72];
    __shared__ float  sRaw[4][72];
    int wv = threadIdx.x >> 6;
    int lane = threadIdx.x & 63;
    int pix = blockIdx.x * 4 + wv;
    int n = pix / HW; int rem = pix % HW;
    int iy = rem / WW; int ix = rem % WW;
    const bf16* om = omr + (size_t)pix * 216;

    for (int e = lane; e < 72; e += 64)
        sRaw[wv][e] = b2f(om[144 + e]);
    __syncthreads();

    for (int e = lane; e < 72; e += 64) {
        int g = e / 9, p = e - 9 * g;
        float mx = -1e30f;
        #pragma unroll
        for (int i = 0; i < 9; ++i) mx = fmaxf(mx, sRaw[wv][g * 9 + i]);
        float ssum = 0.f;
        #pragma unroll
        for (int i = 0; i < 9; ++i) ssum += __expf(sRaw[wv][g * 9 + i] - mx);
        float mw = __expf(sRaw[wv][e] - mx) / ssum;

        float ox = b2f(om[g * 18 + 2 * p]);
        float oy = b2f(om[g * 18 + 2 * p + 1]);
        int kx = p / 3 - 1, ky = p % 3 - 1;  // torch meshgrid 'ij': x slowest
        float px = (float)(ix + kx) + ox;
        float py = (float)(iy + ky) + oy;
        float fx0 = floorf(px), fy0 = floorf(py);
        int x0 = (int)fx0, y0 = (int)fy0;
        float fx = px - fx0, fy = py - fy0;
        bool vx0 = (x0 >= 0) & (x0 < WW), vx1 = (x0 + 1 >= 0) & (x0 + 1 < WW);
        bool vy0 = (y0 >= 0) & (y0 < HH), vy1 = (y0 + 1 >= 0) & (y0 + 1 < HH);
        float w00 = (1.f - fy) * (1.f - fx) * mw * (vy0 && vx0 ? 1.f : 0.f);
        float w01 = (1.f - fy) * fx         * mw * (vy0 && vx1 ? 1.f : 0.f);
        float w10 = fy * (1.f - fx)         * mw * (vy1 && vx0 ? 1.f : 0.f);
        float w11 = fy * fx                 * mw * (vy1 && vx1 ? 1.f : 0.f);
        int x0c = min(max(x0, 0), WW - 1), x1c = min(max(x0 + 1, 0), WW - 1);
        int y0c = min(max(y0, 0), HH - 1), y1c = min(max(y0 + 1, 0), HH - 1);
        sOff[wv][e] = make_int4((y0c * WW + x0c) * CC, (y0c * WW + x1c) * CC,
                                (y1c * WW + x0c) * CC, (y1c * WW + x1c) * CC);
        sW[wv][e] = make_float4(w00, w01, w10, w11);
    }
    __syncthreads();

    const bf16* xb = xproj + (size_t)n * HW * CC + 2 * lane;
    int gbase = (lane >> 3) * 9;
    float a0 = 0.f, a1 = 0.f;
    #pragma unroll
    for (int p = 0; p < 9; ++p) {
        int4 o = sOff[wv][gbase + p];
        float4 w = sW[wv][gbase + p];
        bf162 v00 = *(const bf162*)(xb + o.x);
        bf162 v01 = *(const bf162*)(xb + o.y);
        bf162 v10 = *(const bf162*)(xb + o.z);
        bf162 v11 = *(const bf162*)(xb + o.w);
        a0 += w.x * b2f(v00.x) + w.y * b2f(v01.x) + w.z * b2f(v10.x) + w.w * b2f(v11.x);
        a1 += w.x * b2f(v00.y) + w.y * b2f(v01.y) + w.z * b2f(v10.y) + w.w * b2f(v11.y);
    }
    bf162 o2; o2.x = f2b(a0); o2.y = f2b(a1);
    ((bf162*)out)[(size_t)pix * 64 + lane] = o2;
}

// ---------------- MFMA GEMM (R3-proven): Out[M,N] = A[M,K] @ Wt^T + bias
__global__ __launch_bounds__(256) void gemm_mfma_kernel(
    const bf16* __restrict__ A, const bf16* __restrict__ Wt,
    const float* __restrict__ bias, bf16* __restrict__ Out, int M, int Nn, int K)
{
    __shared__ __align__(16) __bf16 As[64][72];
    __shared__ __align__(16) __bf16 Bs[64][72];
    int tid = threadIdx.x;
    int wv = tid >> 6, lane = tid & 63;
    int bm = blockIdx.y * 64, bn = blockIdx.x * 64;
    int mI = lane & 15, q = lane >> 4;
    floatx4 acc[4] = {};

    for (int k0 = 0; k0 < K; k0 += 64) {
        #pragma unroll
        for (int cc = 0; cc < 2; ++cc) {
            int ch = tid * 2 + cc;               // 0..511
            int row = ch >> 3, ko = (ch & 7) * 8;
            *reinterpret_cast<uint4*>(&As[row][ko]) =
                *reinterpret_cast<const uint4*>(A + (size_t)(bm + row) * K + k0 + ko);
            int ng = bn + row;
            uint4 bv = make_uint4(0, 0, 0, 0);
            if (ng < Nn) bv = *reinterpret_cast<const uint4*>(Wt + (size_t)ng * K + k0 + ko);
            *reinterpret_cast<uint4*>(&Bs[row][ko]) = bv;
        }
        __syncthreads();
        #pragma unroll
        for (int kk = 0; kk < 64; kk += 32) {
            bf16x8 a = *reinterpret_cast<const bf16x8*>(&As[wv * 16 + mI][kk + q * 8]);
            #pragma unroll
            for (int t = 0; t < 4; ++t) {
                bf16x8 b = *reinterpret_cast<const bf16x8*>(&Bs[t * 16 + mI][kk + q * 8]);
                acc[t] = MFMA(a, b, acc[t]);
            }
        }
        __syncthreads();
    }
    int row0 = bm + wv * 16 + q * 4;
    #pragma unroll
    for (int t = 0; t < 4; ++t) {
        int col = bn + t * 16 + mI;
        if (col >= Nn) continue;
        float bs = bias[col];
        #pragma unroll
        for (int r = 0; r < 4; ++r)
            st1(Out + (size_t)(row0 + r) * Nn + col, acc[t][r] + bs);
    }
}

// ---------------- fused tail: xres = x + ycore@w_outT + b_out; h2 = LN2(xres);
// h1 = gelu(h2@w1T + b1); out = xres + h1@w2T + b2.   One block per 64 rows.
// ALL shared buffers FLAT-indexed (R6 bug: 2D sH2 indexed flat -> OOB).
__global__ __launch_bounds__(256, 2) void fused_tail_kernel(
    const bf16* __restrict__ ycore, const float* __restrict__ x,
    const bf16* __restrict__ w_outT, const float* __restrict__ b_out,
    const float* __restrict__ ln2g, const float* __restrict__ ln2b,
    const bf16* __restrict__ w1T, const float* __restrict__ b1,
    const bf16* __restrict__ w2T, const float* __restrict__ b2,
    float* __restrict__ out)
{
    __shared__ __align__(16) bf16 sU[64 * 264];      // ycore[64][136] then h1half[64][264]
    __shared__ __align__(16) bf16 sXres[64 * 136];
    __shared__ __align__(16) bf16 sH2[64 * 136];
    int tid = threadIdx.x, wv = tid >> 6, lane = tid & 63;
    int mI = lane & 15, q = lane >> 4;
    int bm = blockIdx.x * 64;

    // stage ycore tile (64 x 128) at stride 136
    #pragma unroll
    for (int i = 0; i < 4; ++i) {
        int s = tid + 256 * i;
        int row = s >> 4, ko = (s & 15) * 8;
        *reinterpret_cast<uint4*>(&sU[row * 136 + ko]) =
            *reinterpret_cast<const uint4*>(ycore + (size_t)(bm + row) * 128 + ko);
    }
    __syncthreads();

    // GEMM0: wave covers cols wv*32..+31 (2 tiles), all 4 row-tiles
    floatx4 acc0[4][2] = {};
    #pragma unroll
    for (int ks = 0; ks < 4; ++ks) {
        int k = ks * 32 + q * 8;
        bf16x8 a[4];
        #pragma unroll
        for (int rt = 0; rt < 4; ++rt)
            a[rt] = *reinterpret_cast<const bf16x8*>(&sU[(rt * 16 + mI) * 136 + k]);
        #pragma unroll
        for (int ct = 0; ct < 2; ++ct) {
            bf16x8 b = *reinterpret_cast<const bf16x8*>(
                w_outT + (size_t)(wv * 32 + ct * 16 + mI) * 128 + k);
            #pragma unroll
            for (int rt = 0; rt < 4; ++rt) acc0[rt][ct] = MFMA(a[rt], b, acc0[rt][ct]);
        }
    }
    // xres tile -> LDS (bf16), with x residual (f32 global)
    #pragma unroll
    for (int rt = 0; rt < 4; ++rt)
        #pragma unroll
        for (int ct = 0; ct < 2; ++ct) {
            int col = wv * 32 + ct * 16 + mI;
            float bs = b_out[col];
            #pragma unroll
            for (int r = 0; r < 4; ++r) {
                int row = rt * 16 + q * 4 + r;
                float v = acc0[rt][ct][r] + bs + x[(size_t)(bm + row) * 128 + col];
                sXres[row * 136 + col] = f2b(v);
            }
        }
    __syncthreads();

    // LN2: thread -> (row = tid>>2, 32 channels), quad shuffle reduce
    {
        int row = tid >> 2, part = tid & 3;
        float s = 0.f, sq = 0.f;
        float vals[32];
        #pragma unroll
        for (int j = 0; j < 4; ++j) {
            bf16x8 v = *reinterpret_cast<const bf16x8*>(&sXres[row * 136 + part * 32 + j * 8]);
            #pragma unroll
            for (int e = 0; e < 8; ++e) {
                float f = (float)v[e];
                vals[j * 8 + e] = f; s += f; sq += f * f;
            }
        }
        s  += __shfl_xor(s, 1);  s += __shfl_xor(s, 2);
        sq += __shfl_xor(sq, 1); sq += __shfl_xor(sq, 2);
        float mean = s * (1.0f / 128.0f);
        float rstd = rsqrtf(sq * (1.0f / 128.0f) - mean * mean + 1e-5f);
        #pragma unroll
        for (int j = 0; j < 4; ++j) {
            bf16x8 o;
            #pragma unroll
            for (int e = 0; e < 8; ++e) {
                int ch = part * 32 + j * 8 + e;
                bf16 t = f2b((vals[j * 8 + e] - mean) * rstd * ln2g[ch] + ln2b[ch]);
                o[e] = *reinterpret_cast<__bf16*>(&t);
            }
            *reinterpret_cast<bf16x8*>(&sH2[row * 136 + part * 32 + j * 8]) = o;
        }
    }
    __syncthreads();

    // MLP, two half-phases over hidden dim
    floatx4 acc2[4][2] = {};
    for (int h = 0; h < 2; ++h) {
        // GEMM1: wave cols h*256 + wv*64 (4 tiles), all 4 row-tiles, K=128
        floatx4 acc1[4][4] = {};
        #pragma unroll
        for (int ks = 0; ks < 4; ++ks) {
            int k = ks * 32 + q * 8;
            bf16x8 a[4];
            #pragma unroll
            for (int rt = 0; rt < 4; ++rt)
                a[rt] = *reinterpret_cast<const bf16x8*>(&sH2[(rt * 16 + mI) * 136 + k]);
            #pragma unroll
            for (int ct = 0; ct < 4; ++ct) {
                int gcol = h * 256 + wv * 64 + ct * 16 + mI;
                bf16x8 b = *reinterpret_cast<const bf16x8*>(w1T + (size_t)gcol * 128 + k);
                #pragma unroll
                for (int rt = 0; rt < 4; ++rt) acc1[rt][ct] = MFMA(a[rt], b, acc1[rt][ct]);
            }
        }
        // gelu -> h1 half tile in LDS (local cols wv*64..+63)
        #pragma unroll
        for (int rt = 0; rt < 4; ++rt)
            #pragma unroll
            for (int ct = 0; ct < 4; ++ct) {
                int lcol = wv * 64 + ct * 16 + mI;
                float bs = b1[h * 256 + lcol];
                #pragma unroll
                for (int r = 0; r < 4; ++r) {
                    int row = rt * 16 + q * 4 + r;
                    sU[row * 264 + lcol] = f2b(gelu_exact(acc1[rt][ct][r] + bs));
                }
            }
        __syncthreads();
        // GEMM2 partial-K: wave cols wv*32..+31 (2 tiles), K-local = 256
        #pragma unroll
        for (int ks = 0; ks < 8; ++ks) {
            int k = ks * 32 + q * 8;
            bf16x8 a[4];
            #pragma unroll
            for (int rt = 0; rt < 4; ++rt)
                a[rt] = *reinterpret_cast<const bf16x8*>(&sU[(rt * 16 + mI) * 264 + k]);
            #pragma unroll
            for (int ct = 0; ct < 2; ++ct) {
                int ng = wv * 32 + ct * 16 + mI;
                bf16x8 b = *reinterpret_cast<const bf16x8*>(
                    w2T + (size_t)ng * 512 + h * 256 + k);
                #pragma unroll
                for (int rt = 0; rt < 4; ++rt) acc2[rt][ct] = MFMA(a[rt], b, acc2[rt][ct]);
            }
        }
        __syncthreads();   // before next h overwrites sU
    }
    // epilogue: out = acc2 + b2 + xres  (f32)
    #pragma unroll
    for (int rt = 0; rt < 4; ++rt)
        #pragma unroll
        for (int ct = 0; ct < 2; ++ct) {
            int col = wv * 32 + ct * 16 + mI;
            float bs = b2[col];
            #pragma unroll
            for (int r = 0; r < 4; ++r) {
                int row = rt * 16 + q * 4 + r;
                out[(size_t)(bm + row) * 128 + col] =
                    acc2[rt][ct][r] + bs + b2f(sXres[row * 136 + col]);
            }
        }
}

extern "C" void kernel_launch(void* const* d_in, const int* in_sizes, int n_in,
                              void* d_out, int out_size, void* d_ws, size_t ws_size,
                              hipStream_t stream)
{
    const float* x     = (const float*)d_in[0];
    const float* ln1g  = (const float*)d_in[1];
    const float* ln1b  = (const float*)d_in[2];
    const float* w_in  = (const float*)d_in[3];
    const float* b_in  = (const float*)d_in[4];
    const float* dw_k  = (const float*)d_in[5];
    const float* dw_b  = (const float*)d_in[6];
    const float* dwg   = (const float*)d_in[7];
    const float* dwb   = (const float*)d_in[8];
    const float* w_off = (const float*)d_in[9];
    const float* b_off = (const float*)d_in[10];
    const float* w_msk = (const float*)d_in[11];
    const float* b_msk = (const float*)d_in[12];
    const float* w_out = (const float*)d_in[13];
    const float* b_out = (const float*)d_in[14];
    const float* ln2g  = (const float*)d_in[15];
    const float* ln2b  = (const float*)d_in[16];
    const float* w1    = (const float*)d_in[17];
    const float* b1    = (const float*)d_in[18];
    const float* w2    = (const float*)d_in[19];
    const float* b2    = (const float*)d_in[20];
    float* out = (float*)d_out;

    // activations (bf16): xln(128)->ycore | xproj(128) | x1(128) | omr(216)
    bf16* ws = (bf16*)d_ws;
    bf16* xln   = ws;
    bf16* xproj = xln   + (size_t)NPIX * 128;
    bf16* x1    = xproj + (size_t)NPIX * 128;
    bf16* omr   = x1    + (size_t)NPIX * 128;
    bf16* ycore = xln;                  // xln dead after dwconv
    // bf16 transposed weights after activations (600/pix)
    bf16* wT    = ws + (size_t)NPIX * 600;
    bf16* w_inT  = wT;                  // 128x128
    bf16* w_omT  = w_inT  + 16384;      // 216x128 (off 144 + msk 72)
    bf16* w_outT = w_omT  + 27648;      // 128x128
    bf16* w1T    = w_outT + 16384;      // 512x128
    bf16* w2T    = w1T    + 65536;      // 128x512
    float* b_om  = (float*)(w2T + 65536);  // 216 f32
    const int WTOT = 191488 + 216;

    PrepArgs pa;
    pa.src[0] = w_in;  pa.dst[0] = w_inT;            pa.K[0] = 128; pa.N[0] = 128;
    pa.src[1] = w_off; pa.dst[1] = w_omT;            pa.K[1] = 128; pa.N[1] = 144;
    pa.src[2] = w_msk; pa.dst[2] = w_omT + 144*128;  pa.K[2] = 128; pa.N[2] = 72;
    pa.src[3] = w_out; pa.dst[3] = w_outT;           pa.K[3] = 128; pa.N[3] = 128;
    pa.src[4] = w1;    pa.dst[4] = w1T;              pa.K[4] = 128; pa.N[4] = 512;
    pa.src[5] = w2;    pa.dst[5] = w2T;              pa.K[5] = 512; pa.N[5] = 128;
    pa.cum[0] = 0;     pa.cum[1] = 16384;  pa.cum[2] = 34816; pa.cum[3] = 44032;
    pa.cum[4] = 60416; pa.cum[5] = 125952; pa.cum[6] = 191488;
    pa.b_off = b_off;  pa.b_msk = b_msk;   pa.b_om = b_om;

    const int M = NPIX;          // 36864
    dim3 blk(256);

    // 0. weight prep (+ bias concat)
    prep_weights<<<(WTOT + 255) / 256, blk, 0, stream>>>(pa, WTOT);
    // 1. xln = LN1(x)
    ln_kernel<float, bf16><<<NPIX / 4, blk, 0, stream>>>(x, ln1g, ln1b, xln);
    // 2. xproj = xln @ w_in + b_in
    gemm_mfma_kernel<<<dim3(2, M / 64), blk, 0, stream>>>(
        xln, w_inT, b_in, xproj, M, 128, 128);
    // 3. x1 = gelu(LN(dwconv(xln) + dw_b))
    dwconv_ln_gelu_kernel<<<NPIX / 4, blk, 0, stream>>>(xln, dw_k, dw_b, dwg, dwb, x1);
    // 4. omr = x1 @ [w_off | w_msk] + [b_off | b_msk]   (N=216 fused)
    gemm_mfma_kernel<<<dim3(4, M / 64), blk, 0, stream>>>(
        x1, w_omT, b_om, omr, M, 216, 128);
    // 5. ycore = dcnv3(xproj, omr)  [softmax fused in]
    dcn_core_kernel<<<NPIX / 4, blk, 0, stream>>>(xproj, omr, ycore);
    // 6-9. fused: outproj + residual + LN2 + MLP + residual
    fused_tail_kernel<<<M / 64, blk, 0, stream>>>(
        ycore, x, w_outT, b_out, ln2g, ln2b, w1T, b1, w2T, b2, out);
}

// Round 8
// 236.881 us; speedup vs baseline: 1.4264x; 1.0352x over previous
//
#include <hip/hip_runtime.h>
#include <hip/hip_bf16.h>
#include <math.h>

using bf16 = __hip_bfloat16;
using bf162 = __hip_bfloat162;

typedef __bf16 bf16x8 __attribute__((ext_vector_type(8)));
typedef float floatx4 __attribute__((ext_vector_type(4)));

constexpr int NB = 4, HH = 96, WW = 96, CC = 128, GG = 8, PP = 9;
constexpr int HW = HH * WW;          // 9216
constexpr int NPIX = NB * HW;        // 36864

__device__ __forceinline__ float ld1(const float* p) { return *p; }
__device__ __forceinline__ float ld1(const bf16* p)  { return __bfloat162float(*p); }
__device__ __forceinline__ void st1(float* p, float v) { *p = v; }
__device__ __forceinline__ void st1(bf16* p, float v)  { *p = __float2bfloat16(v); }
__device__ __forceinline__ float b2f(bf16 v) { return __bfloat162float(v); }
__device__ __forceinline__ bf16 f2b(float v) { return __float2bfloat16(v); }
__device__ __forceinline__ float gelu_exact(float v) {
    return 0.5f * v * (1.0f + erff(v * 0.7071067811865475f));
}
__device__ __forceinline__ floatx4 MFMA(bf16x8 a, bf16x8 b, floatx4 c) {
    return __builtin_amdgcn_mfma_f32_16x16x32_bf16(a, b, c, 0, 0, 0);
}

// ---------------- one-time weight prep: f32 W[K][N] -> bf16 Wt[N][K] (+ bias concat)
struct PrepArgs {
    const float* src[6];
    bf16* dst[6];
    int K[6], N[6];
    int cum[7];
    const float* b_off; const float* b_msk; float* b_om;   // bias concat 216
};

__global__ __launch_bounds__(256) void prep_weights(PrepArgs pa, int total)
{
    int t = blockIdx.x * 256 + threadIdx.x;
    if (t >= total) return;
    if (t >= pa.cum[6]) {                 // bias concat tail
        int e = t - pa.cum[6];
        pa.b_om[e] = (e < 144) ? pa.b_off[e] : pa.b_msk[e - 144];
        return;
    }
    int i = 0;
    #pragma unroll
    for (int j = 0; j < 5; ++j) if (t >= pa.cum[j + 1]) i = j + 1;
    int e = t - pa.cum[i];
    int Ki = pa.K[i], Ni = pa.N[i];
    int n = e / Ki, k = e - n * Ki;
    pa.dst[i][e] = f2b(pa.src[i][(size_t)k * Ni + n]);
}

// ---------------- LayerNorm over C=128, one wave per pixel, 2 ch/lane
template<typename TI, typename TO>
__global__ __launch_bounds__(256) void ln_kernel(
    const TI* __restrict__ X, const float* __restrict__ g,
    const float* __restrict__ b, TO* __restrict__ out)
{
    int wave = (blockIdx.x * 256 + threadIdx.x) >> 6;
    int lane = threadIdx.x & 63;
    if (wave >= NPIX) return;
    const TI* xp = X + (size_t)wave * 128 + 2 * lane;
    float v0 = ld1(xp), v1 = ld1(xp + 1);
    float s = v0 + v1, q = v0 * v0 + v1 * v1;
    #pragma unroll
    for (int o = 32; o; o >>= 1) { s += __shfl_xor(s, o); q += __shfl_xor(q, o); }
    float mean = s * (1.0f / 128.0f);
    float rstd = rsqrtf(q * (1.0f / 128.0f) - mean * mean + 1e-5f);
    float g0 = g[2 * lane], g1 = g[2 * lane + 1];
    float b0 = b[2 * lane], b1 = b[2 * lane + 1];
    TO* op = out + (size_t)wave * 128 + 2 * lane;
    st1(op,     (v0 - mean) * rstd * g0 + b0);
    st1(op + 1, (v1 - mean) * rstd * g1 + b1);
}

// ---------------- depthwise 3x3 conv (SAME, zero pad) + LN + exact GELU. wave/pixel
__global__ __launch_bounds__(256) void dwconv_ln_gelu_kernel(
    const bf16* __restrict__ xln, const float* __restrict__ dwk,
    const float* __restrict__ dwb, const float* __restrict__ gam,
    const float* __restrict__ bet, bf16* __restrict__ out)
{
    int wave = (blockIdx.x * 256 + threadIdx.x) >> 6;
    int lane = threadIdx.x & 63;
    if (wave >= NPIX) return;
    int n = wave / HW; int rem = wave % HW;
    int y = rem / WW;  int x = rem % WW;
    const bf162* xp = (const bf162*)xln;
    float a0 = 0.f, a1 = 0.f;
    #pragma unroll
    for (int ky = 0; ky < 3; ++ky) {
        int yy = y + ky - 1;
        if (yy < 0 || yy >= HH) continue;
        #pragma unroll
        for (int kx = 0; kx < 3; ++kx) {
            int xx = x + kx - 1;
            if (xx < 0 || xx >= WW) continue;
            bf162 v = xp[((size_t)(n * HH + yy) * WW + xx) * 64 + lane];
            const float* w = dwk + (ky * 3 + kx) * CC + 2 * lane;
            a0 = fmaf(b2f(v.x), w[0], a0);
            a1 = fmaf(b2f(v.y), w[1], a1);
        }
    }
    a0 += dwb[2 * lane]; a1 += dwb[2 * lane + 1];
    float s = a0 + a1, q = a0 * a0 + a1 * a1;
    #pragma unroll
    for (int o = 32; o; o >>= 1) { s += __shfl_xor(s, o); q += __shfl_xor(q, o); }
    float mean = s * (1.0f / 128.0f);
    float rstd = rsqrtf(q * (1.0f / 128.0f) - mean * mean + 1e-5f);
    float h0 = gelu_exact((a0 - mean) * rstd * gam[2 * lane]     + bet[2 * lane]);
    float h1 = gelu_exact((a1 - mean) * rstd * gam[2 * lane + 1] + bet[2 * lane + 1]);
    bf162 o2; o2.x = f2b(h0); o2.y = f2b(h1);
    ((bf162*)out)[(size_t)wave * 64 + lane] = o2;
}

// ---------------- DCNv3 core: wave per pixel, fused mask-softmax + two-phase
__global__ __launch_bounds__(256) void dcn_core_kernel(
    const bf16* __restrict__ xproj, const bf16* __restrict__ omr,
    bf16* __restrict__ out)
{
    __shared__ int4   sOff[4][72];
    __shared__ float4 sW[4][72];
    __shared__ float  sRaw[4][72];
    int wv = threadIdx.x >> 6;
    int lane = threadIdx.x & 63;
    int pix = blockIdx.x * 4 + wv;
    int n = pix / HW; int rem = pix % HW;
    int iy = rem / WW; int ix = rem % WW;
    const bf16* om = omr + (size_t)pix * 216;

    for (int e = lane; e < 72; e += 64)
        sRaw[wv][e] = b2f(om[144 + e]);
    __syncthreads();

    for (int e = lane; e < 72; e += 64) {
        int g = e / 9, p = e - 9 * g;
        float mx = -1e30f;
        #pragma unroll
        for (int i = 0; i < 9; ++i) mx = fmaxf(mx, sRaw[wv][g * 9 + i]);
        float ssum = 0.f;
        #pragma unroll
        for (int i = 0; i < 9; ++i) ssum += __expf(sRaw[wv][g * 9 + i] - mx);
        float mw = __expf(sRaw[wv][e] - mx) / ssum;

        float ox = b2f(om[g * 18 + 2 * p]);
        float oy = b2f(om[g * 18 + 2 * p + 1]);
        int kx = p / 3 - 1, ky = p % 3 - 1;  // torch meshgrid 'ij': x slowest
        float px = (float)(ix + kx) + ox;
        float py = (float)(iy + ky) + oy;
        float fx0 = floorf(px), fy0 = floorf(py);
        int x0 = (int)fx0, y0 = (int)fy0;
        float fx = px - fx0, fy = py - fy0;
        bool vx0 = (x0 >= 0) & (x0 < WW), vx1 = (x0 + 1 >= 0) & (x0 + 1 < WW);
        bool vy0 = (y0 >= 0) & (y0 < HH), vy1 = (y0 + 1 >= 0) & (y0 + 1 < HH);
        float w00 = (1.f - fy) * (1.f - fx) * mw * (vy0 && vx0 ? 1.f : 0.f);
        float w01 = (1.f - fy) * fx         * mw * (vy0 && vx1 ? 1.f : 0.f);
        float w10 = fy * (1.f - fx)         * mw * (vy1 && vx0 ? 1.f : 0.f);
        float w11 = fy * fx                 * mw * (vy1 && vx1 ? 1.f : 0.f);
        int x0c = min(max(x0, 0), WW - 1), x1c = min(max(x0 + 1, 0), WW - 1);
        int y0c = min(max(y0, 0), HH - 1), y1c = min(max(y0 + 1, 0), HH - 1);
        sOff[wv][e] = make_int4((y0c * WW + x0c) * CC, (y0c * WW + x1c) * CC,
                                (y1c * WW + x0c) * CC, (y1c * WW + x1c) * CC);
        sW[wv][e] = make_float4(w00, w01, w10, w11);
    }
    __syncthreads();

    const bf16* xb = xproj + (size_t)n * HW * CC + 2 * lane;
    int gbase = (lane >> 3) * 9;
    float a0 = 0.f, a1 = 0.f;
    #pragma unroll
    for (int p = 0; p < 9; ++p) {
        int4 o = sOff[wv][gbase + p];
        float4 w = sW[wv][gbase + p];
        bf162 v00 = *(const bf162*)(xb + o.x);
        bf162 v01 = *(const bf162*)(xb + o.y);
        bf162 v10 = *(const bf162*)(xb + o.z);
        bf162 v11 = *(const bf162*)(xb + o.w);
        a0 += w.x * b2f(v00.x) + w.y * b2f(v01.x) + w.z * b2f(v10.x) + w.w * b2f(v11.x);
        a1 += w.x * b2f(v00.y) + w.y * b2f(v01.y) + w.z * b2f(v10.y) + w.w * b2f(v11.y);
    }
    bf162 o2; o2.x = f2b(a0); o2.y = f2b(a1);
    ((bf162*)out)[(size_t)pix * 64 + lane] = o2;
}

// ---------------- MFMA GEMM (R3-proven): Out[M,N] = A[M,K] @ Wt^T + bias
__global__ __launch_bounds__(256) void gemm_mfma_kernel(
    const bf16* __restrict__ A, const bf16* __restrict__ Wt,
    const float* __restrict__ bias, bf16* __restrict__ Out, int M, int Nn, int K)
{
    __shared__ __align__(16) __bf16 As[64][72];
    __shared__ __align__(16) __bf16 Bs[64][72];
    int tid = threadIdx.x;
    int wv = tid >> 6, lane = tid & 63;
    int bm = blockIdx.y * 64, bn = blockIdx.x * 64;
    int mI = lane & 15, q = lane >> 4;
    floatx4 acc[4] = {};

    for (int k0 = 0; k0 < K; k0 += 64) {
        #pragma unroll
        for (int cc = 0; cc < 2; ++cc) {
            int ch = tid * 2 + cc;               // 0..511
            int row = ch >> 3, ko = (ch & 7) * 8;
            *reinterpret_cast<uint4*>(&As[row][ko]) =
                *reinterpret_cast<const uint4*>(A + (size_t)(bm + row) * K + k0 + ko);
            int ng = bn + row;
            uint4 bv = make_uint4(0, 0, 0, 0);
            if (ng < Nn) bv = *reinterpret_cast<const uint4*>(Wt + (size_t)ng * K + k0 + ko);
            *reinterpret_cast<uint4*>(&Bs[row][ko]) = bv;
        }
        __syncthreads();
        #pragma unroll
        for (int kk = 0; kk < 64; kk += 32) {
            bf16x8 a = *reinterpret_cast<const bf16x8*>(&As[wv * 16 + mI][kk + q * 8]);
            #pragma unroll
            for (int t = 0; t < 4; ++t) {
                bf16x8 b = *reinterpret_cast<const bf16x8*>(&Bs[t * 16 + mI][kk + q * 8]);
                acc[t] = MFMA(a, b, acc[t]);
            }
        }
        __syncthreads();
    }
    int row0 = bm + wv * 16 + q * 4;
    #pragma unroll
    for (int t = 0; t < 4; ++t) {
        int col = bn + t * 16 + mI;
        if (col >= Nn) continue;
        float bs = bias[col];
        #pragma unroll
        for (int r = 0; r < 4; ++r)
            st1(Out + (size_t)(row0 + r) * Nn + col, acc[t][r] + bs);
    }
}

// ---------------- fused tail, v2: quarter-phase MLP + hoisted B-frag loads.
// xres = x + ycore@w_outT + b_out; h2 = LN2(xres); h1 = gelu(h2@w1T + b1);
// out = xres + h1@w2T + b2.  One block per 64 rows; LDS 52.2 KB -> 3 blocks/CU.
__global__ __launch_bounds__(256, 3) void fused_tail_kernel(
    const bf16* __restrict__ ycore, const float* __restrict__ x,
    const bf16* __restrict__ w_outT, const float* __restrict__ b_out,
    const float* __restrict__ ln2g, const float* __restrict__ ln2b,
    const bf16* __restrict__ w1T, const float* __restrict__ b1,
    const bf16* __restrict__ w2T, const float* __restrict__ b2,
    float* __restrict__ out)
{
    __shared__ __align__(16) bf16 sA[64 * 136];      // ycore stage, then h1 quarter
    __shared__ __align__(16) bf16 sXres[64 * 136];
    __shared__ __align__(16) bf16 sH2[64 * 136];
    int tid = threadIdx.x, wv = tid >> 6, lane = tid & 63;
    int mI = lane & 15, q = lane >> 4;
    int bm = blockIdx.x * 64;

    // prefetch GEMM0 B-frags (8 independent 16B loads, in flight during staging)
    bf16x8 bw0[4][2];
    #pragma unroll
    for (int ks = 0; ks < 4; ++ks)
        #pragma unroll
        for (int ct = 0; ct < 2; ++ct)
            bw0[ks][ct] = *reinterpret_cast<const bf16x8*>(
                w_outT + (size_t)(wv * 32 + ct * 16 + mI) * 128 + ks * 32 + q * 8);

    // stage ycore tile (64 x 128) at stride 136
    #pragma unroll
    for (int i = 0; i < 4; ++i) {
        int s = tid + 256 * i;
        int row = s >> 4, ko = (s & 15) * 8;
        *reinterpret_cast<uint4*>(&sA[row * 136 + ko]) =
            *reinterpret_cast<const uint4*>(ycore + (size_t)(bm + row) * 128 + ko);
    }
    __syncthreads();

    // GEMM0: wave covers out-proj cols wv*32..+31
    floatx4 acc0[4][2] = {};
    #pragma unroll
    for (int ks = 0; ks < 4; ++ks) {
        int k = ks * 32 + q * 8;
        bf16x8 a[4];
        #pragma unroll
        for (int rt = 0; rt < 4; ++rt)
            a[rt] = *reinterpret_cast<const bf16x8*>(&sA[(rt * 16 + mI) * 136 + k]);
        #pragma unroll
        for (int ct = 0; ct < 2; ++ct)
            #pragma unroll
            for (int rt = 0; rt < 4; ++rt)
                acc0[rt][ct] = MFMA(a[rt], bw0[ks][ct], acc0[rt][ct]);
    }
    // xres tile -> sXres (bf16), with x residual (f32 global)
    #pragma unroll
    for (int rt = 0; rt < 4; ++rt)
        #pragma unroll
        for (int ct = 0; ct < 2; ++ct) {
            int col = wv * 32 + ct * 16 + mI;
            float bs = b_out[col];
            #pragma unroll
            for (int r = 0; r < 4; ++r) {
                int row = rt * 16 + q * 4 + r;
                float v = acc0[rt][ct][r] + bs + x[(size_t)(bm + row) * 128 + col];
                sXres[row * 136 + col] = f2b(v);
            }
        }
    __syncthreads();

    // LN2: thread -> (row = tid>>2, 32 channels), quad shuffle reduce
    {
        int row = tid >> 2, part = tid & 3;
        float s = 0.f, sq = 0.f;
        float vals[32];
        #pragma unroll
        for (int j = 0; j < 4; ++j) {
            bf16x8 v = *reinterpret_cast<const bf16x8*>(&sXres[row * 136 + part * 32 + j * 8]);
            #pragma unroll
            for (int e = 0; e < 8; ++e) {
                float f = (float)v[e];
                vals[j * 8 + e] = f; s += f; sq += f * f;
            }
        }
        s  += __shfl_xor(s, 1);  s += __shfl_xor(s, 2);
        sq += __shfl_xor(sq, 1); sq += __shfl_xor(sq, 2);
        float mean = s * (1.0f / 128.0f);
        float rstd = rsqrtf(sq * (1.0f / 128.0f) - mean * mean + 1e-5f);
        #pragma unroll
        for (int j = 0; j < 4; ++j) {
            bf16x8 o;
            #pragma unroll
            for (int e = 0; e < 8; ++e) {
                int ch = part * 32 + j * 8 + e;
                bf16 t = f2b((vals[j * 8 + e] - mean) * rstd * ln2g[ch] + ln2b[ch]);
                o[e] = *reinterpret_cast<__bf16*>(&t);
            }
            *reinterpret_cast<bf16x8*>(&sH2[row * 136 + part * 32 + j * 8]) = o;
        }
    }
    __syncthreads();

    // MLP in four 128-col quarter-phases over the hidden dim
    floatx4 acc2[4][2] = {};
    #pragma unroll 1
    for (int ph = 0; ph < 4; ++ph) {
        // hoist GEMM1 B-frags (hidden cols ph*128 + wv*32..+31): 8 loads in flight
        bf16x8 bw1[4][2];
        #pragma unroll
        for (int ks = 0; ks < 4; ++ks)
            #pragma unroll
            for (int ct = 0; ct < 2; ++ct)
                bw1[ks][ct] = *reinterpret_cast<const bf16x8*>(
                    w1T + (size_t)(ph * 128 + wv * 32 + ct * 16 + mI) * 128 + ks * 32 + q * 8);
        // GEMM1: h1 quarter cols wv*32..+31
        floatx4 acc1[4][2] = {};
        #pragma unroll
        for (int ks = 0; ks < 4; ++ks) {
            int k = ks * 32 + q * 8;
            bf16x8 a[4];
            #pragma unroll
            for (int rt = 0; rt < 4; ++rt)
                a[rt] = *reinterpret_cast<const bf16x8*>(&sH2[(rt * 16 + mI) * 136 + k]);
            #pragma unroll
            for (int ct = 0; ct < 2; ++ct)
                #pragma unroll
                for (int rt = 0; rt < 4; ++rt)
                    acc1[rt][ct] = MFMA(a[rt], bw1[ks][ct], acc1[rt][ct]);
        }
        __syncthreads();   // all waves done reading sA from previous phase
        // hoist GEMM2 B-frags now; they fly during the gelu VALU burst
        bf16x8 bw2[4][2];
        #pragma unroll
        for (int ks = 0; ks < 4; ++ks)
            #pragma unroll
            for (int ct = 0; ct < 2; ++ct)
                bw2[ks][ct] = *reinterpret_cast<const bf16x8*>(
                    w2T + (size_t)(wv * 32 + ct * 16 + mI) * 512 + ph * 128 + ks * 32 + q * 8);
        // gelu -> sA (h1 quarter, local cols wv*32..+31)
        #pragma unroll
        for (int rt = 0; rt < 4; ++rt)
            #pragma unroll
            for (int ct = 0; ct < 2; ++ct) {
                int lcol = wv * 32 + ct * 16 + mI;
                float bs = b1[ph * 128 + lcol];
                #pragma unroll
                for (int r = 0; r < 4; ++r) {
                    int row = rt * 16 + q * 4 + r;
                    sA[row * 136 + lcol] = f2b(gelu_exact(acc1[rt][ct][r] + bs));
                }
            }
        __syncthreads();
        // GEMM2 partial-K: out cols wv*32..+31, K-local = 128
        #pragma unroll
        for (int ks = 0; ks < 4; ++ks) {
            int k = ks * 32 + q * 8;
            bf16x8 a[4];
            #pragma unroll
            for (int rt = 0; rt < 4; ++rt)
                a[rt] = *reinterpret_cast<const bf16x8*>(&sA[(rt * 16 + mI) * 136 + k]);
            #pragma unroll
            for (int ct = 0; ct < 2; ++ct)
                #pragma unroll
                for (int rt = 0; rt < 4; ++rt)
                    acc2[rt][ct] = MFMA(a[rt], bw2[ks][ct], acc2[rt][ct]);
        }
    }
    // epilogue: out = acc2 + b2 + xres  (f32)
    #pragma unroll
    for (int rt = 0; rt < 4; ++rt)
        #pragma unroll
        for (int ct = 0; ct < 2; ++ct) {
            int col = wv * 32 + ct * 16 + mI;
            float bs = b2[col];
            #pragma unroll
            for (int r = 0; r < 4; ++r) {
                int row = rt * 16 + q * 4 + r;
                out[(size_t)(bm + row) * 128 + col] =
                    acc2[rt][ct][r] + bs + b2f(sXres[row * 136 + col]);
            }
        }
}

extern "C" void kernel_launch(void* const* d_in, const int* in_sizes, int n_in,
                              void* d_out, int out_size, void* d_ws, size_t ws_size,
                              hipStream_t stream)
{
    const float* x     = (const float*)d_in[0];
    const float* ln1g  = (const float*)d_in[1];
    const float* ln1b  = (const float*)d_in[2];
    const float* w_in  = (const float*)d_in[3];
    const float* b_in  = (const float*)d_in[4];
    const float* dw_k  = (const float*)d_in[5];
    const float* dw_b  = (const float*)d_in[6];
    const float* dwg   = (const float*)d_in[7];
    const float* dwb   = (const float*)d_in[8];
    const float* w_off = (const float*)d_in[9];
    const float* b_off = (const float*)d_in[10];
    const float* w_msk = (const float*)d_in[11];
    const float* b_msk = (const float*)d_in[12];
    const float* w_out = (const float*)d_in[13];
    const float* b_out = (const float*)d_in[14];
    const float* ln2g  = (const float*)d_in[15];
    const float* ln2b  = (const float*)d_in[16];
    const float* w1    = (const float*)d_in[17];
    const float* b1    = (const float*)d_in[18];
    const float* w2    = (const float*)d_in[19];
    const float* b2    = (const float*)d_in[20];
    float* out = (float*)d_out;

    // activations (bf16): xln(128)->ycore | xproj(128) | x1(128) | omr(216)
    bf16* ws = (bf16*)d_ws;
    bf16* xln   = ws;
    bf16* xproj = xln   + (size_t)NPIX * 128;
    bf16* x1    = xproj + (size_t)NPIX * 128;
    bf16* omr   = x1    + (size_t)NPIX * 128;
    bf16* ycore = xln;                  // xln dead after dwconv
    // bf16 transposed weights after activations (600/pix)
    bf16* wT    = ws + (size_t)NPIX * 600;
    bf16* w_inT  = wT;                  // 128x128
    bf16* w_omT  = w_inT  + 16384;      // 216x128 (off 144 + msk 72)
    bf16* w_outT = w_omT  + 27648;      // 128x128
    bf16* w1T    = w_outT + 16384;      // 512x128
    bf16* w2T    = w1T    + 65536;      // 128x512
    float* b_om  = (float*)(w2T + 65536);  // 216 f32
    const int WTOT = 191488 + 216;

    PrepArgs pa;
    pa.src[0] = w_in;  pa.dst[0] = w_inT;            pa.K[0] = 128; pa.N[0] = 128;
    pa.src[1] = w_off; pa.dst[1] = w_omT;            pa.K[1] = 128; pa.N[1] = 144;
    pa.src[2] = w_msk; pa.dst[2] = w_omT + 144*128;  pa.K[2] = 128; pa.N[2] = 72;
    pa.src[3] = w_out; pa.dst[3] = w_outT;           pa.K[3] = 128; pa.N[3] = 128;
    pa.src[4] = w1;    pa.dst[4] = w1T;              pa.K[4] = 128; pa.N[4] = 512;
    pa.src[5] = w2;    pa.dst[5] = w2T;              pa.K[5] = 512; pa.N[5] = 128;
    pa.cum[0] = 0;     pa.cum[1] = 16384;  pa.cum[2] = 34816; pa.cum[3] = 44032;
    pa.cum[4] = 60416; pa.cum[5] = 125952; pa.cum[6] = 191488;
    pa.b_off = b_off;  pa.b_msk = b_msk;   pa.b_om = b_om;

    const int M = NPIX;          // 36864
    dim3 blk(256);

    // 0. weight prep (+ bias concat)
    prep_weights<<<(WTOT + 255) / 256, blk, 0, stream>>>(pa, WTOT);
    // 1. xln = LN1(x)
    ln_kernel<float, bf16><<<NPIX / 4, blk, 0, stream>>>(x, ln1g, ln1b, xln);
    // 2. xproj = xln @ w_in + b_in
    gemm_mfma_kernel<<<dim3(2, M / 64), blk, 0, stream>>>(
        xln, w_inT, b_in, xproj, M, 128, 128);
    // 3. x1 = gelu(LN(dwconv(xln) + dw_b))
    dwconv_ln_gelu_kernel<<<NPIX / 4, blk, 0, stream>>>(xln, dw_k, dw_b, dwg, dwb, x1);
    // 4. omr = x1 @ [w_off | w_msk] + [b_off | b_msk]   (N=216 fused)
    gemm_mfma_kernel<<<dim3(4, M / 64), blk, 0, stream>>>(
        x1, w_omT, b_om, omr, M, 216, 128);
    // 5. ycore = dcnv3(xproj, omr)  [softmax fused in]
    dcn_core_kernel<<<NPIX / 4, blk, 0, stream>>>(xproj, omr, ycore);
    // 6-9. fused: outproj + residual + LN2 + MLP + residual
    fused_tail_kernel<<<M / 64, blk, 0, stream>>>(
        ycore, x, w_outT, b_out, ln2g, ln2b, w1T, b1, w2T, b2, out);
}